// Round 3
// baseline (433.683 us; speedup 1.0000x reference)
//
#include <hip/hip_runtime.h>

#define BB 32
#define TT 2000
#define HH 512
#define LL 256
#define THRESH 0.95f

// d_ws layout:
//   float scale[BB]       : per-batch alpha rescale factor
//   int   nfires[BB]      : number of fires (clamped to LL)
//   int4  rec[BB*LL]      : per-fire record {t, bits(dist), bits(remainds), 0}

__global__ __launch_bounds__(256) void cif_scan_kernel(
    const float* __restrict__ alphas, const int* __restrict__ tlen,
    float* __restrict__ scale_out, int* __restrict__ nfires,
    int4* __restrict__ rec)
{
    __shared__ double red[8][256];
    __shared__ float sscale[BB];
    const int tid = threadIdx.x;

    // Phase 1: row sums. EXACT same per-batch grouping/order as the passing
    // round-1/2 kernel (thread k sums t=k,k+256,...; 256-wide pairwise tree),
    // so scale[] is bit-identical and no fire decision can flip.
    for (int p = 0; p < 4; ++p) {
        for (int bb = 0; bb < 8; ++bb) {
            const int b = p * 8 + bb;
            const float* arow = alphas + b * TT;
            double s = 0.0;
            for (int t = tid; t < TT; t += 256) s += (double)arow[t];
            red[bb][tid] = s;
        }
        __syncthreads();
        for (int off = 128; off > 0; off >>= 1) {
            if (tid < off) {
                #pragma unroll
                for (int bb = 0; bb < 8; ++bb)
                    red[bb][tid] += red[bb][tid + off];
            }
            __syncthreads();
        }
        if (tid < 8) {
            const int b = p * 8 + tid;
            const float sumf = (float)red[tid][0];
            const float sc = (float)tlen[b] / sumf;   // f32 divide, as reference
            sscale[b] = sc;
            scale_out[b] = sc;
        }
        __syncthreads();
    }

    // Phase 2: lockstep serial scan — lane b (0..31) of wave 0 replays batch b.
    // All 32 batches share one wave's instruction issue; fire handling is
    // exec-masked, not branched per batch.
    if (tid >= 32) return;
    const int b = tid;
    const float sc = sscale[b];
    const float4* a4 = (const float4*)(alphas + b * TT);   // 500 groups
    int4* rb = rec + b * LL;

    float4 buf[8];                    // 32-step rolling prefetch (global, L2-hot)
    #pragma unroll
    for (int i = 0; i < 8; ++i) buf[i] = a4[i];

    float integ = 0.0f;
    int nf = 0;
    for (int cg = 0; cg < 63; ++cg) {
        #pragma unroll
        for (int i = 0; i < 8; ++i) {
            const int g = cg * 8 + i;
            if (g < TT / 4) {
                float4 c = buf[i];
                if (g + 8 < TT / 4) buf[i] = a4[g + 8];
                const float av[4] = {c.x * sc, c.y * sc, c.z * sc, c.w * sc};
                #pragma unroll
                for (int j = 0; j < 4; ++j) {
                    const float a = av[j];
                    const float dist = 1.0f - integ;   // from OLD integrate
                    float ii = integ + a;              // integrate += alpha
                    const bool fire = (ii >= THRESH);
                    if (fire) {                        // exec-masked, short body
                        if (nf < LL) {
                            int4 r;
                            r.x = g * 4 + j;
                            r.y = __float_as_int(dist);        // w_self at fire
                            r.z = __float_as_int(a - dist);    // remainds
                            r.w = 0;
                            rb[nf] = r;
                        }
                        nf++;
                        ii -= 1.0f;
                    }
                    integ = ii;
                }
            }
        }
    }
    nfires[b] = (nf < LL) ? nf : LL;
}

__global__ __launch_bounds__(128) void cif_gather_kernel(
    const float* __restrict__ hidden, const float* __restrict__ alphas,
    const float* __restrict__ scale, const int4* __restrict__ rec,
    const int* __restrict__ nfires, float* __restrict__ out)
{
    const int l = blockIdx.x;       // token index
    const int b = blockIdx.y;       // batch
    const int tid = threadIdx.x;    // 128 threads x float4 = 512 = HH

    float4 acc = make_float4(0.f, 0.f, 0.f, 0.f);
    const int F = nfires[b];
    if (l < F) {
        const int4 re = rec[b * LL + l];
        const int e = re.x;                        // fire step of this token
        const float dist = __int_as_float(re.y);   // weight of frame e
        const float sc = scale[b];
        const float* hb = hidden + (size_t)b * TT * HH + (size_t)tid * 4;
        const float* ab = alphas + b * TT;
        int t0 = 0;
        if (l > 0) {
            const int4 rp = rec[b * LL + l - 1];
            const int sp = rp.x;
            const float rem = __int_as_float(rp.z);   // remainds seeds frame
            const float4 hv0 = *(const float4*)(hb + (size_t)sp * HH);
            acc.x = rem * hv0.x; acc.y = rem * hv0.y;
            acc.z = rem * hv0.z; acc.w = rem * hv0.w;
            t0 = sp + 1;
        }
        // Interior weights recomputed as alphas[t]*sc — bit-identical to the
        // scan's values. Ascending t, same accumulation order as reference.
        // Depth-1 software pipeline (no loop-carried vmcnt(0)).
        int t = t0;
        float w = (t < e) ? ab[t] * sc : dist;
        float4 hv = *(const float4*)(hb + (size_t)t * HH);
        while (t < e) {
            const float wN = (t + 1 < e) ? ab[t + 1] * sc : dist;
            const float4 hN = *(const float4*)(hb + (size_t)(t + 1) * HH);
            acc.x += w * hv.x; acc.y += w * hv.y;
            acc.z += w * hv.z; acc.w += w * hv.w;
            w = wN; hv = hN; ++t;
        }
        acc.x += w * hv.x; acc.y += w * hv.y;
        acc.z += w * hv.z; acc.w += w * hv.w;
    }
    *(float4*)(out + ((size_t)b * LL + l) * HH + (size_t)tid * 4) = acc;
}

extern "C" void kernel_launch(void* const* d_in, const int* in_sizes, int n_in,
                              void* d_out, int out_size, void* d_ws, size_t ws_size,
                              hipStream_t stream) {
    const float* hidden = (const float*)d_in[0];   // [B,T,H] f32
    const float* alphas = (const float*)d_in[1];   // [B,T]   f32
    const int*   tlen   = (const int*)d_in[2];     // [B]     i32
    float* out = (float*)d_out;                    // [B,L,H] f32

    float* scale  = (float*)d_ws;
    int*   nfires = (int*)(scale + BB);
    int4*  rec    = (int4*)(nfires + BB);          // 256B offset, 16B-aligned

    cif_scan_kernel<<<1, 256, 0, stream>>>(alphas, tlen, scale, nfires, rec);
    cif_gather_kernel<<<dim3(LL, BB), 128, 0, stream>>>(hidden, alphas, scale,
                                                        rec, nfires, out);
}

// Round 4
// 263.072 us; speedup vs baseline: 1.6485x; 1.6485x over previous
//
#include <hip/hip_runtime.h>

#define BB 32
#define TT 2000
#define NG 500          // float4 groups per alphas row
#define HH 512
#define LL 256
#define THRESH 0.95f

// d_ws layout:
//   float cur[BB*TT]      : per-step frame weight (alpha, or dist at fires)
//   int   fire_pos[BB*LL] : time index of the l-th fire per batch
//   int   nfires[BB]      : number of fires (clamped to LL)
//   float scale[BB]       : per-batch alpha rescale factor

__global__ __launch_bounds__(256) void cif_scan_kernel(
    const float* __restrict__ alphas, const int* __restrict__ tlen,
    float* __restrict__ cur_g, int* __restrict__ fire_pos,
    int* __restrict__ nfires, float* __restrict__ scale_g)
{
    const int b = blockIdx.x;
    const int tid = threadIdx.x;
    __shared__ float sa[TT];       // scaled alphas (input to scan)
    __shared__ float scur[TT];     // cur output
    __shared__ double red[256];
    __shared__ int fp_s[LL];
    __shared__ float s_scale;
    __shared__ int s_nf;

    // ---- load row -> LDS + f64 row sum (f64 slack >> f32 ulp, so the
    // f32-rounded sum is bit-stable across groupings; rounds 1-3 validated
    // the double-sum -> f32-divide path). ----
    const float4* a4 = (const float4*)(alphas + b * TT);
    float4* sa4 = (float4*)sa;
    double s = 0.0;
    for (int g = tid; g < NG; g += 256) {
        float4 v = a4[g];
        sa4[g] = v;
        s += (double)v.x + (double)v.y + (double)v.z + (double)v.w;
    }
    red[tid] = s;
    __syncthreads();
    for (int off = 128; off > 0; off >>= 1) {
        if (tid < off) red[tid] += red[tid + off];
        __syncthreads();
    }
    if (tid == 0) {
        const float sumf = (float)red[0];
        const float sc = (float)tlen[b] / sumf;   // f32 divide, as reference
        s_scale = sc;
        scale_g[b] = sc;
    }
    __syncthreads();
    const float sc = s_scale;

    // ---- pre-scale in parallel (takes the mul off the serial lane; same
    // f32 mul the gather uses to recompute rem -> bit-identical). ----
    for (int g = tid; g < NG; g += 256) {
        float4 v = sa4[g];
        v.x *= sc; v.y *= sc; v.z *= sc; v.w *= sc;
        sa4[g] = v;
    }
    __syncthreads();

    // ---- serial scan on thread 0: LDS-fed register pipeline, branchy fire
    // path (taken ~8% of steps on a 1-lane wave), no global traffic. ----
    if (tid == 0) {
        float integ = 0.0f;
        int nf = 0;
        const float4* s4 = (const float4*)sa;
        float4* c4 = (float4*)scur;
        float4 buf[4];
        #pragma unroll
        for (int i = 0; i < 4; ++i) buf[i] = s4[i];
        for (int blk = 0; blk < 125; ++blk) {      // 125 x 4 groups = 2000 steps
            #pragma unroll
            for (int i = 0; i < 4; ++i) {
                const int g = blk * 4 + i;
                const float4 c = buf[i];
                if (g + 4 < NG) buf[i] = s4[g + 4];   // prefetch 4 groups ahead
                const float av[4] = {c.x, c.y, c.z, c.w};
                float ov[4];
                #pragma unroll
                for (int j = 0; j < 4; ++j) {
                    const float a = av[j];
                    float ii = integ + a;          // integrate += alpha
                    float o = a;
                    if (ii >= THRESH) {            // fire (rare on 1 lane)
                        o = 1.0f - integ;          // dist from OLD integrate
                        ii -= 1.0f;
                        if (nf < LL) fp_s[nf] = g * 4 + j;
                        nf++;
                    }
                    ov[j] = o;
                    integ = ii;
                }
                c4[g] = make_float4(ov[0], ov[1], ov[2], ov[3]);
            }
        }
        s_nf = (nf < LL) ? nf : LL;
    }
    __syncthreads();

    // ---- coalesced flush ----
    const int nf = s_nf;
    if (tid == 0) nfires[b] = nf;
    float4* cg4 = (float4*)(cur_g + b * TT);
    const float4* sc4 = (const float4*)scur;
    for (int g = tid; g < NG; g += 256) cg4[g] = sc4[g];
    if (tid < LL) fire_pos[b * LL + tid] = (tid < nf) ? fp_s[tid] : 0;
}

__global__ __launch_bounds__(128) void cif_gather_kernel(
    const float* __restrict__ hidden, const float* __restrict__ alphas,
    const float* __restrict__ cur_g, const float* __restrict__ scale_g,
    const int* __restrict__ fire_pos, const int* __restrict__ nfires,
    float* __restrict__ out)
{
    const int l = blockIdx.x;       // token index
    const int b = blockIdx.y;       // batch
    const int tid = threadIdx.x;    // 128 threads x float4 = 512 = HH

    float4 acc = make_float4(0.f, 0.f, 0.f, 0.f);
    const int F = nfires[b];
    if (l < F) {
        const int e = fire_pos[b * LL + l];          // fire step of this token
        const float* hb = hidden + (size_t)b * TT * HH + (size_t)tid * 4;
        const float* wb = cur_g + b * TT;
        int t0 = 0;
        if (l > 0) {
            const int sp = fire_pos[b * LL + l - 1];
            const float a_sp = alphas[b * TT + sp] * scale_g[b];
            const float rem = a_sp - wb[sp];         // a - dist, bit-exact
            const float4 hv = *(const float4*)(hb + (size_t)sp * HH);
            acc.x = rem * hv.x; acc.y = rem * hv.y;
            acc.z = rem * hv.z; acc.w = rem * hv.w;
            t0 = sp + 1;
        }
        // Ascending t (reference accumulation order), depth-2 load pipeline.
        int t = t0;
        float w0 = wb[t];
        float4 h0 = *(const float4*)(hb + (size_t)t * HH);
        if (t < e) {
            float w1 = wb[t + 1];
            float4 h1 = *(const float4*)(hb + (size_t)(t + 1) * HH);
            while (t + 2 <= e) {
                const float w2 = wb[t + 2];
                const float4 h2 = *(const float4*)(hb + (size_t)(t + 2) * HH);
                acc.x += w0 * h0.x; acc.y += w0 * h0.y;
                acc.z += w0 * h0.z; acc.w += w0 * h0.w;
                w0 = w1; h0 = h1; w1 = w2; h1 = h2; ++t;
            }
            acc.x += w0 * h0.x; acc.y += w0 * h0.y;
            acc.z += w0 * h0.z; acc.w += w0 * h0.w;
            w0 = w1; h0 = h1;
        }
        acc.x += w0 * h0.x; acc.y += w0 * h0.y;
        acc.z += w0 * h0.z; acc.w += w0 * h0.w;
    }
    *(float4*)(out + ((size_t)b * LL + l) * HH + (size_t)tid * 4) = acc;
}

extern "C" void kernel_launch(void* const* d_in, const int* in_sizes, int n_in,
                              void* d_out, int out_size, void* d_ws, size_t ws_size,
                              hipStream_t stream) {
    const float* hidden = (const float*)d_in[0];   // [B,T,H] f32
    const float* alphas = (const float*)d_in[1];   // [B,T]   f32
    const int*   tlen   = (const int*)d_in[2];     // [B]     i32
    float* out = (float*)d_out;                    // [B,L,H] f32

    float* cur_g    = (float*)d_ws;
    int*   fire_pos = (int*)(cur_g + BB * TT);
    int*   nfires   = fire_pos + BB * LL;
    float* scale_g  = (float*)(nfires + BB);

    cif_scan_kernel<<<BB, 256, 0, stream>>>(alphas, tlen, cur_g, fire_pos,
                                            nfires, scale_g);
    cif_gather_kernel<<<dim3(LL, BB), 128, 0, stream>>>(hidden, alphas, cur_g,
                                                        scale_g, fire_pos,
                                                        nfires, out);
}